// Round 3
// baseline (380.364 us; speedup 1.0000x reference)
//
#include <hip/hip_runtime.h>

#define B_    2
#define N_TOK 2048
#define C_    1024
#define H_    16
#define D_    64
#define M_    (B_*N_TOK)   // 4096
#define N3C   3072

typedef unsigned short u16;
typedef unsigned int   u32;

typedef __attribute__((ext_vector_type(8))) short bf16x8;
typedef __attribute__((ext_vector_type(4))) short bf16x4;
typedef __attribute__((ext_vector_type(4))) float f32x4;

__device__ __forceinline__ u16 f2bf(float f) {       // RNE
  u32 u = __float_as_uint(f);
  return (u16)((u + 0x7FFFu + ((u >> 16) & 1u)) >> 16);
}
__device__ __forceinline__ u16 f2bf_fast(float f) {  // round-half-up (P only)
  return (u16)((__float_as_uint(f) + 0x8000u) >> 16);
}

// K=16 bf16 MFMA: D[m][n] += sum_{k<16} A[m][k]*B[n][k]; A/B frag = 4 bf16/lane
__device__ __forceinline__ f32x4 mfma16(bf16x4 a, bf16x4 b, f32x4 c) {
#if __has_builtin(__builtin_amdgcn_mfma_f32_16x16x16_bf16)
  return __builtin_amdgcn_mfma_f32_16x16x16_bf16(a, b, c, 0, 0, 0);
#elif __has_builtin(__builtin_amdgcn_mfma_f32_16x16x16bf16_1k)
  return __builtin_amdgcn_mfma_f32_16x16x16bf16_1k(a, b, c, 0, 0, 0);
#else
  asm("v_mfma_f32_16x16x16_bf16 %0, %1, %2, %0" : "+v"(c) : "v"(a), "v"(b));
  return c;
#endif
}

// async global->LDS, 16B per lane
__device__ __forceinline__ void async16(const u16* g, u16* l) {
  __builtin_amdgcn_global_load_lds(
      (const __attribute__((address_space(1))) u32*)g,
      (__attribute__((address_space(3))) u32*)l, 16, 0, 0);
}

// ---------------- fp32 -> bf16 convert ----------------
__global__ void k_f32_to_bf16(const float* __restrict__ in, u16* __restrict__ out) {
  int i = (blockIdx.x * 256 + threadIdx.x) * 4;
  float4 v = *(const float4*)(in + i);
  *(ushort4*)(out + i) = make_ushort4(f2bf(v.x), f2bf(v.y), f2bf(v.z), f2bf(v.w));
}

// ---------------- GEMM1: qkv = x @ w_qkv^T + b ----------------
// Q -> [B,H,N,D] pre-scaled by 0.125*log2(e); K -> [B,H,N,D];
// V -> [B,H,D,Nswz]: within each 32-key group, key (par*16+qdk*4+i) stored at
// (qdk*8+par*4+i) so one 16B load at qd*8 yields two K=16 B-fragments.
__global__ __launch_bounds__(256) void k_gemm_qkv(
    const u16* __restrict__ A, const u16* __restrict__ Bm,
    const float* __restrict__ bias,
    u16* __restrict__ qout, u16* __restrict__ kout, u16* __restrict__ vout)
{
  __shared__ u16 As[128*32];
  __shared__ u16 Bs[128*32];
  const int K = C_;
  int bm = blockIdx.x, bn = blockIdx.y;
  int tid = threadIdx.x;
  int lane = tid & 63, wave = tid >> 6;
  int wrow = (wave >> 1) * 64, wcol = (wave & 1) * 64;
  int qd = lane >> 4, ln = lane & 15;

  f32x4 zero = {0.f, 0.f, 0.f, 0.f};
  f32x4 acc[4][4];
  for (int i = 0; i < 4; i++) for (int j = 0; j < 4; j++) acc[i][j] = zero;

  const u16* Ab = A  + (size_t)bm * 128 * K;
  const u16* Bb = Bm + (size_t)bn * 128 * K;

  for (int k0 = 0; k0 < K; k0 += 32) {
    __syncthreads();
    for (int j = 0; j < 2; j++) {
      int slot = (wave*2 + j)*64 + lane;
      int r = slot >> 2, c = (slot & 3) * 8;
      async16(&Ab[(size_t)r * K + k0 + c], &As[(wave*2 + j) * 512]);
      async16(&Bb[(size_t)r * K + k0 + c], &Bs[(wave*2 + j) * 512]);
    }
    __syncthreads();
    bf16x8 af[4], bfr[4];
    for (int mi = 0; mi < 4; mi++) af[mi]  = *(const bf16x8*)&As[(wrow + mi*16 + ln)*32 + qd*8];
    for (int ni = 0; ni < 4; ni++) bfr[ni] = *(const bf16x8*)&Bs[(wcol + ni*16 + ln)*32 + qd*8];
    for (int mi = 0; mi < 4; mi++)
      for (int ni = 0; ni < 4; ni++)
        acc[mi][ni] = __builtin_amdgcn_mfma_f32_16x16x32_bf16(af[mi], bfr[ni], acc[mi][ni], 0, 0, 0);
  }

  for (int ni = 0; ni < 4; ni++) {
    int nbase = bn*128 + wcol + ni*16 + ln;
    int three = nbase >> 10;        // wave-uniform
    int h = (nbase >> 6) & 15;
    int d = nbase & 63;
    float bv = bias[nbase];
    if (three == 2) {
      for (int mi = 0; mi < 4; mi++) {
        int row0 = bm*128 + wrow + mi*16 + qd*4;
        int b = row0 >> 11, t0 = row0 & 2047;
        int g = t0 >> 5, w = t0 & 31;
        int qdk = (w >> 2) & 3, par = w >> 4;
        int pos = g*32 + qdk*8 + par*4;
        u16 tmp[4];
        for (int r = 0; r < 4; r++) tmp[r] = f2bf(acc[mi][ni][r] + bv);
        *(ushort4*)&vout[(((size_t)(b*H_ + h))*D_ + d)*N_TOK + pos] = *(ushort4*)tmp;
      }
    } else {
      u16* dst = three ? kout : qout;
      float sc = three ? 1.0f : 0.18033688011f;  // 0.125*log2(e) folded into Q
      for (int mi = 0; mi < 4; mi++) {
        for (int r = 0; r < 4; r++) {
          int row = bm*128 + wrow + mi*16 + qd*4 + r;
          int b = row >> 11, t = row & 2047;
          dst[(((size_t)(b*H_ + h))*N_TOK + t)*D_ + d] = f2bf((acc[mi][ni][r] + bv) * sc);
        }
      }
    }
  }
}

// ---------------- flash attention: zero LDS, zero barriers ----------------
// wave = 16 q-rows; block = 64 rows; grid 1024 (XCD-swizzled) -> 4 blocks/CU.
// S^T = MFMA(A=K, B=Q): C-layout lane(qd,ln) holds P[q=ln][key=qd*4+r], which IS
// the A-fragment of the K=16 MFMA -> PV straight from registers.
__global__ __launch_bounds__(256, 4) void k_attn(
    const u16* __restrict__ Q, const u16* __restrict__ Kk, const u16* __restrict__ Vt,
    u16* __restrict__ Oa)   // [B*N][C] bf16
{
  int ord = blockIdx.x;                 // 0..1023
  int xcd = ord & 7, kk = ord >> 3;     // kk 0..127
  int bh = xcd * 4 + (kk & 3);          // 4 heads per XCD -> K/V L2-resident
  int qt = kk >> 2;                     // 0..31
  int b = bh >> 4, h = bh & 15;
  int tid = threadIdx.x, lane = tid & 63, wave = tid >> 6;
  int qd = lane >> 4, ln = lane & 15;

  const u16* Qg = Q  + ((size_t)bh * N_TOK + qt*64 + wave*16) * D_;
  const u16* Kg = Kk + (size_t)bh * N_TOK * D_;
  const u16* Vg = Vt + (size_t)bh * D_ * N_TOK;

  bf16x8 qf[2];
  for (int ks = 0; ks < 2; ks++)
    qf[ks] = *(const bf16x8*)&Qg[ln*D_ + ks*32 + qd*8];

  f32x4 z = {0.f, 0.f, 0.f, 0.f};
  f32x4 oacc[4];
  for (int di = 0; di < 4; di++) oacc[di] = z;
  float lsum = 0.f;

  for (int kt = 0; kt < N_TOK/64; kt++) {
    // all loads issued first (hide behind S-MFMA + exp of this iter / other waves)
    const u16* Ktile = Kg + (size_t)kt * 64 * D_;
    bf16x8 kf[4][2];
    for (int nt = 0; nt < 4; nt++)
      for (int ks = 0; ks < 2; ks++)
        kf[nt][ks] = *(const bf16x8*)&Ktile[(nt*16 + ln)*D_ + ks*32 + qd*8];
    bf16x8 v8[4][2];
    for (int di = 0; di < 4; di++)
      for (int hf = 0; hf < 2; hf++)
        v8[di][hf] = *(const bf16x8*)&Vg[(size_t)(di*16 + ln)*N_TOK + (2*kt + hf)*32 + qd*8];

    // S^T [key 16][q 16] tiles: A = K-frag, B = Q-frag
    f32x4 sacc[4];
    for (int nt = 0; nt < 4; nt++) {
      sacc[nt] = z;
      for (int ks = 0; ks < 2; ks++)
        sacc[nt] = __builtin_amdgcn_mfma_f32_16x16x32_bf16(kf[nt][ks], qf[ks], sacc[nt], 0, 0, 0);
    }

    // P = exp2(S') in-register; lane(qd,ln) -> P[q=ln][key=nt*16+qd*4+i] = K=16 A-frag
    bf16x4 pf[4];
    for (int nt = 0; nt < 4; nt++) {
      for (int i = 0; i < 4; i++) {
        float e = __builtin_amdgcn_exp2f(sacc[nt][i]);
        lsum += e;
        pf[nt][i] = (short)f2bf_fast(e);
      }
    }

    // O += P @ V  (K=16 MFMAs, V frags unpacked from swizzled 16B loads)
    for (int di = 0; di < 4; di++) {
      for (int nt = 0; nt < 4; nt++) {
        int hf = nt >> 1, s = (nt & 1) * 4;
        bf16x4 vv;
        vv[0] = v8[di][hf][s+0]; vv[1] = v8[di][hf][s+1];
        vv[2] = v8[di][hf][s+2]; vv[3] = v8[di][hf][s+3];
        oacc[di] = mfma16(pf[nt], vv, oacc[di]);
      }
    }
  }

  // row-sum: per-lane partial covers q=ln, keys {qd*4+r mod 16}; reduce across quads
  lsum += __shfl_xor(lsum, 16, 64);
  lsum += __shfl_xor(lsum, 32, 64);
  float rl[4];
  for (int r = 0; r < 4; r++)
    rl[r] = 1.0f / __shfl(lsum, qd*4 + r, 64);   // l for q-row qd*4+r

  for (int di = 0; di < 4; di++)
    for (int r = 0; r < 4; r++) {
      int t = qt*64 + wave*16 + qd*4 + r;
      Oa[((size_t)b*N_TOK + t)*C_ + h*D_ + di*16 + ln] = f2bf(oacc[di][r] * rl[r]);
    }
}

// ---------------- GEMM2: out = attn @ w_out^T + b_out (fp32 out) ----------------
__global__ __launch_bounds__(256) void k_gemm_out(
    const u16* __restrict__ A, const u16* __restrict__ Bm,
    const float* __restrict__ bias, float* __restrict__ out)
{
  __shared__ u16 As[128*32];
  __shared__ u16 Bs[128*32];
  const int K = C_;
  int bm = blockIdx.x, bn = blockIdx.y;
  int tid = threadIdx.x;
  int lane = tid & 63, wave = tid >> 6;
  int wrow = (wave >> 1) * 64, wcol = (wave & 1) * 64;
  int qd = lane >> 4, ln = lane & 15;

  f32x4 zero = {0.f, 0.f, 0.f, 0.f};
  f32x4 acc[4][4];
  for (int i = 0; i < 4; i++) for (int j = 0; j < 4; j++) acc[i][j] = zero;

  const u16* Ab = A  + (size_t)bm * 128 * K;
  const u16* Bb = Bm + (size_t)bn * 128 * K;

  for (int k0 = 0; k0 < K; k0 += 32) {
    __syncthreads();
    for (int j = 0; j < 2; j++) {
      int slot = (wave*2 + j)*64 + lane;
      int r = slot >> 2, c = (slot & 3) * 8;
      async16(&Ab[(size_t)r * K + k0 + c], &As[(wave*2 + j) * 512]);
      async16(&Bb[(size_t)r * K + k0 + c], &Bs[(wave*2 + j) * 512]);
    }
    __syncthreads();
    bf16x8 af[4], bfr[4];
    for (int mi = 0; mi < 4; mi++) af[mi]  = *(const bf16x8*)&As[(wrow + mi*16 + ln)*32 + qd*8];
    for (int ni = 0; ni < 4; ni++) bfr[ni] = *(const bf16x8*)&Bs[(wcol + ni*16 + ln)*32 + qd*8];
    for (int mi = 0; mi < 4; mi++)
      for (int ni = 0; ni < 4; ni++)
        acc[mi][ni] = __builtin_amdgcn_mfma_f32_16x16x32_bf16(af[mi], bfr[ni], acc[mi][ni], 0, 0, 0);
  }

  for (int ni = 0; ni < 4; ni++) {
    int col = bn*128 + wcol + ni*16 + ln;
    float bv = bias[col];
    for (int mi = 0; mi < 4; mi++)
      for (int r = 0; r < 4; r++) {
        int row = bm*128 + wrow + mi*16 + qd*4 + r;
        out[(size_t)row * C_ + col] = acc[mi][ni][r] + bv;
      }
  }
}

extern "C" void kernel_launch(void* const* d_in, const int* in_sizes, int n_in,
                              void* d_out, int out_size, void* d_ws, size_t ws_size,
                              hipStream_t stream) {
  const float* x     = (const float*)d_in[0];
  const float* w_qkv = (const float*)d_in[1];
  const float* b_qkv = (const float*)d_in[2];
  const float* w_out = (const float*)d_in[3];
  const float* b_out = (const float*)d_in[4];
  float* out = (float*)d_out;

  char* ws = (char*)d_ws;
  u16* x_bf    = (u16*)(ws);
  u16* wqkv_bf = (u16*)(ws + (size_t)8*1024*1024);
  u16* wout_bf = (u16*)(ws + (size_t)14*1024*1024);
  u16* q_bf    = (u16*)(ws + (size_t)16*1024*1024);  // [B,H,N,D], pre-scaled
  u16* k_bf    = (u16*)(ws + (size_t)24*1024*1024);  // [B,H,N,D]
  u16* vt_bf   = (u16*)(ws + (size_t)32*1024*1024);  // [B,H,D,N] swizzled
  u16* a_bf    = (u16*)(ws + (size_t)40*1024*1024);  // [M][C]

  k_f32_to_bf16<<<4096, 256, 0, stream>>>(x, x_bf);
  k_f32_to_bf16<<<3072, 256, 0, stream>>>(w_qkv, wqkv_bf);
  k_f32_to_bf16<<<1024, 256, 0, stream>>>(w_out, wout_bf);
  k_gemm_qkv<<<dim3(32, 24), 256, 0, stream>>>(x_bf, wqkv_bf, b_qkv, q_bf, k_bf, vt_bf);
  k_attn<<<1024, 256, 0, stream>>>(q_bf, k_bf, vt_bf, a_bf);
  k_gemm_out<<<dim3(32, 8), 256, 0, stream>>>(a_bf, wout_bf, b_out, out);
}

// Round 4
// 199.351 us; speedup vs baseline: 1.9080x; 1.9080x over previous
//
#include <hip/hip_runtime.h>

#define B_    2
#define N_TOK 2048
#define C_    1024
#define H_    16
#define D_    64
#define M_    (B_*N_TOK)   // 4096
#define N3C   3072

typedef unsigned short u16;
typedef unsigned int   u32;

typedef __attribute__((ext_vector_type(8))) short bf16x8;
typedef __attribute__((ext_vector_type(4))) short bf16x4;
typedef __attribute__((ext_vector_type(4))) float f32x4;

__device__ __forceinline__ u16 f2bf(float f) {       // RNE
  u32 u = __float_as_uint(f);
  return (u16)((u + 0x7FFFu + ((u >> 16) & 1u)) >> 16);
}
__device__ __forceinline__ u16 f2bf_fast(float f) {  // round-half-up (P only)
  return (u16)((__float_as_uint(f) + 0x8000u) >> 16);
}

// K=16 bf16 MFMA
__device__ __forceinline__ f32x4 mfma16(bf16x4 a, bf16x4 b, f32x4 c) {
#if __has_builtin(__builtin_amdgcn_mfma_f32_16x16x16_bf16)
  return __builtin_amdgcn_mfma_f32_16x16x16_bf16(a, b, c, 0, 0, 0);
#elif __has_builtin(__builtin_amdgcn_mfma_f32_16x16x16bf16_1k)
  return __builtin_amdgcn_mfma_f32_16x16x16bf16_1k(a, b, c, 0, 0, 0);
#else
  asm("v_mfma_f32_16x16x16_bf16 %0, %1, %2, %0" : "+v"(c) : "v"(a), "v"(b));
  return c;
#endif
}

// async global->LDS, 16B/lane; LDS dest = wave-uniform base + lane*16
__device__ __forceinline__ void async16(const u16* g, u16* l) {
  __builtin_amdgcn_global_load_lds(
      (const __attribute__((address_space(1))) u32*)g,
      (__attribute__((address_space(3))) u32*)l, 16, 0, 0);
}

// ---------------- fp32 -> bf16 convert ----------------
__global__ void k_f32_to_bf16(const float* __restrict__ in, u16* __restrict__ out) {
  int i = (blockIdx.x * 256 + threadIdx.x) * 4;
  float4 v = *(const float4*)(in + i);
  *(ushort4*)(out + i) = make_ushort4(f2bf(v.x), f2bf(v.y), f2bf(v.z), f2bf(v.w));
}

// ---------------- GEMM1: qkv = x @ w_qkv^T + b ----------------
// Q -> [B,H,N,D] pre-scaled by 0.125*log2(e).
// K -> blocked [bh][kt:32][c:8][row:64][e:8]: elem (key=kt*64+row, d=c*8+e).
// V -> blocked [bh][kt:32][c:8][drow:64][e:8], keys swizzled within tile:
//     key hf*32+par*16+qdk*4+i stored at chunk c=hf*4+qdk, elem par*4+i.
__global__ __launch_bounds__(256) void k_gemm_qkv(
    const u16* __restrict__ A, const u16* __restrict__ Bm,
    const float* __restrict__ bias,
    u16* __restrict__ qout, u16* __restrict__ kout, u16* __restrict__ vout)
{
  __shared__ u16 As[128*32];
  __shared__ u16 Bs[128*32];
  const int K = C_;
  int bm = blockIdx.x, bn = blockIdx.y;
  int tid = threadIdx.x;
  int lane = tid & 63, wave = tid >> 6;
  int wrow = (wave >> 1) * 64, wcol = (wave & 1) * 64;
  int qd = lane >> 4, ln = lane & 15;

  f32x4 zero = {0.f, 0.f, 0.f, 0.f};
  f32x4 acc[4][4];
  for (int i = 0; i < 4; i++) for (int j = 0; j < 4; j++) acc[i][j] = zero;

  const u16* Ab = A  + (size_t)bm * 128 * K;
  const u16* Bb = Bm + (size_t)bn * 128 * K;

  for (int k0 = 0; k0 < K; k0 += 32) {
    __syncthreads();
    for (int j = 0; j < 2; j++) {
      int slot = (wave*2 + j)*64 + lane;
      int r = slot >> 2, c = (slot & 3) * 8;
      async16(&Ab[(size_t)r * K + k0 + c], &As[(wave*2 + j) * 512]);
      async16(&Bb[(size_t)r * K + k0 + c], &Bs[(wave*2 + j) * 512]);
    }
    __syncthreads();
    bf16x8 af[4], bfr[4];
    for (int mi = 0; mi < 4; mi++) af[mi]  = *(const bf16x8*)&As[(wrow + mi*16 + ln)*32 + qd*8];
    for (int ni = 0; ni < 4; ni++) bfr[ni] = *(const bf16x8*)&Bs[(wcol + ni*16 + ln)*32 + qd*8];
    for (int mi = 0; mi < 4; mi++)
      for (int ni = 0; ni < 4; ni++)
        acc[mi][ni] = __builtin_amdgcn_mfma_f32_16x16x32_bf16(af[mi], bfr[ni], acc[mi][ni], 0, 0, 0);
  }

  for (int ni = 0; ni < 4; ni++) {
    int nbase = bn*128 + wcol + ni*16 + ln;
    int three = nbase >> 10;        // wave-uniform
    int h = (nbase >> 6) & 15;
    int d = nbase & 63;
    float bv = bias[nbase];
    if (three == 2) {
      // V blocked+swizzled; 4 consecutive keys -> one 8B store
      for (int mi = 0; mi < 4; mi++) {
        int row0 = bm*128 + wrow + mi*16 + qd*4;
        int b = row0 >> 11, t0 = row0 & 2047;
        int kt = t0 >> 6, w64 = t0 & 63;
        int hf = w64 >> 5, w = w64 & 31, par = w >> 4, qdk = (w >> 2) & 3;
        u16 tmp[4];
        for (int r = 0; r < 4; r++) tmp[r] = f2bf(acc[mi][ni][r] + bv);
        size_t off = (((size_t)(b*H_ + h)*32 + kt)*8 + (hf*4 + qdk))*512 + d*8 + par*4;
        *(ushort4*)&vout[off] = *(ushort4*)tmp;
      }
    } else if (three == 1) {
      // K blocked
      int c = d >> 3, e = d & 7;
      for (int mi = 0; mi < 4; mi++) {
        for (int r = 0; r < 4; r++) {
          int row = bm*128 + wrow + mi*16 + qd*4 + r;
          int b = row >> 11, t = row & 2047;
          int kt = t >> 6, r64 = t & 63;
          kout[(((size_t)(b*H_ + h)*32 + kt)*8 + c)*512 + r64*8 + e] = f2bf(acc[mi][ni][r] + bv);
        }
      }
    } else {
      float sc = 0.18033688011f;  // 0.125*log2(e) folded into Q
      for (int mi = 0; mi < 4; mi++) {
        for (int r = 0; r < 4; r++) {
          int row = bm*128 + wrow + mi*16 + qd*4 + r;
          int b = row >> 11, t = row & 2047;
          qout[(((size_t)(b*H_ + h))*N_TOK + t)*D_ + d] = f2bf((acc[mi][ni][r] + bv) * sc);
        }
      }
    }
  }
}

// ---------------- flash attention: LDS-staged K/V, register-resident P ----------------
// block = 4 waves x 32 q-rows = 128 rows; grid 512 (XCD-swizzled) -> 2 blocks/CU.
// K/V tiles staged once per block via coalesced global_load_lds, shared by 4 waves.
// S^T trick: P exits QK^T MFMA directly in the K=16 MFMA A-operand layout.
__global__ __launch_bounds__(256, 2) void k_attn(
    const u16* __restrict__ Q, const u16* __restrict__ Kb, const u16* __restrict__ Vb,
    u16* __restrict__ Oa)   // [B*N][C] bf16
{
  __shared__ u16 Ks[4096];   // [c:8][row:64][e:8]
  __shared__ u16 Vs[4096];   // [c:8][drow:64][e:8] (keys swizzled)
  int ord = blockIdx.x;                 // 0..511
  int xcd = ord & 7, kk = ord >> 3;     // kk 0..63
  int bh = xcd * 4 + (kk & 3);          // 4 heads per XCD
  int qt = kk >> 2;                     // 0..15
  int b = bh >> 4, h = bh & 15;
  int tid = threadIdx.x, lane = tid & 63, wave = tid >> 6;
  int qd = lane >> 4, ln = lane & 15;

  const u16* Qg = Q  + ((size_t)bh * N_TOK + qt*128 + wave*32) * D_;
  const u16* Kg = Kb + (size_t)bh * 32 * 4096;
  const u16* Vg = Vb + (size_t)bh * 32 * 4096;

  // loop-invariant Q B-fragments (pre-scaled), 2 strips of 16 rows
  bf16x8 qf[2][2];
  for (int mi = 0; mi < 2; mi++)
    for (int ks = 0; ks < 2; ks++)
      qf[mi][ks] = *(const bf16x8*)&Qg[(mi*16 + ln)*D_ + ks*32 + qd*8];

  f32x4 z = {0.f, 0.f, 0.f, 0.f};
  f32x4 oacc[2][4];
  float lsum[2] = {0.f, 0.f};
  for (int mi = 0; mi < 2; mi++) for (int di = 0; di < 4; di++) oacc[mi][di] = z;

  for (int kt = 0; kt < 32; kt++) {
    __syncthreads();   // prior-iter LDS reads complete
    const u16* Ktile = Kg + (size_t)kt * 4096;
    const u16* Vtile = Vg + (size_t)kt * 4096;
    for (int j = 0; j < 2; j++) {
      int c0 = j*256 + wave*64;        // 16B-chunk base (wave-uniform)
      async16(&Ktile[(c0 + lane)*8], &Ks[c0*8]);
      async16(&Vtile[(c0 + lane)*8], &Vs[c0*8]);
    }
    __syncthreads();   // staging visible to all waves

    bf16x8 kf[4][2];
    for (int nt = 0; nt < 4; nt++)
      for (int ks = 0; ks < 2; ks++)
        kf[nt][ks] = *(const bf16x8*)&Ks[((ks*4 + qd)*64 + nt*16 + ln)*8];
    bf16x8 v8[4][2];
    for (int di = 0; di < 4; di++)
      for (int hf = 0; hf < 2; hf++)
        v8[di][hf] = *(const bf16x8*)&Vs[((hf*4 + qd)*64 + di*16 + ln)*8];

    // S^T tiles: A = K-frag (from LDS), B = Q-frag (register)
    f32x4 sacc[2][4];
    for (int mi = 0; mi < 2; mi++)
      for (int nt = 0; nt < 4; nt++) {
        sacc[mi][nt] = z;
        for (int ks = 0; ks < 2; ks++)
          sacc[mi][nt] = __builtin_amdgcn_mfma_f32_16x16x32_bf16(kf[nt][ks], qf[mi][ks], sacc[mi][nt], 0, 0, 0);
      }

    // P = exp2(S'); lane(qd,ln) holds P[q=ln][key=nt*16+qd*4+i] = K=16 A-frag
    bf16x4 pf[2][4];
    for (int mi = 0; mi < 2; mi++)
      for (int nt = 0; nt < 4; nt++)
        for (int i = 0; i < 4; i++) {
          float e = __builtin_amdgcn_exp2f(sacc[mi][nt][i]);
          lsum[mi] += e;
          pf[mi][nt][i] = (short)f2bf_fast(e);
        }

    // O += P @ V (K=16 MFMAs; V frags unpacked from swizzled 16B LDS reads)
    for (int mi = 0; mi < 2; mi++)
      for (int di = 0; di < 4; di++)
        for (int nt = 0; nt < 4; nt++) {
          int hf = nt >> 1, s = (nt & 1) * 4;
          bf16x4 vv;
          vv[0] = v8[di][hf][s+0]; vv[1] = v8[di][hf][s+1];
          vv[2] = v8[di][hf][s+2]; vv[3] = v8[di][hf][s+3];
          oacc[mi][di] = mfma16(pf[mi][nt], vv, oacc[mi][di]);
        }
  }

  // row sums: lane partial covers q=ln; reduce over qd (lanes ln+16k)
  for (int mi = 0; mi < 2; mi++) {
    float ls = lsum[mi];
    ls += __shfl_xor(ls, 16, 64);
    ls += __shfl_xor(ls, 32, 64);
    float rl[4];
    for (int r = 0; r < 4; r++)
      rl[r] = 1.0f / __shfl(ls, qd*4 + r, 64);
    for (int di = 0; di < 4; di++)
      for (int r = 0; r < 4; r++) {
        int t = qt*128 + wave*32 + mi*16 + qd*4 + r;
        Oa[((size_t)b*N_TOK + t)*C_ + h*D_ + di*16 + ln] = f2bf(oacc[mi][di][r] * rl[r]);
      }
  }
}

// ---------------- GEMM2: out = attn @ w_out^T + b_out (fp32 out) ----------------
__global__ __launch_bounds__(256) void k_gemm_out(
    const u16* __restrict__ A, const u16* __restrict__ Bm,
    const float* __restrict__ bias, float* __restrict__ out)
{
  __shared__ u16 As[128*32];
  __shared__ u16 Bs[128*32];
  const int K = C_;
  int bm = blockIdx.x, bn = blockIdx.y;
  int tid = threadIdx.x;
  int lane = tid & 63, wave = tid >> 6;
  int wrow = (wave >> 1) * 64, wcol = (wave & 1) * 64;
  int qd = lane >> 4, ln = lane & 15;

  f32x4 zero = {0.f, 0.f, 0.f, 0.f};
  f32x4 acc[4][4];
  for (int i = 0; i < 4; i++) for (int j = 0; j < 4; j++) acc[i][j] = zero;

  const u16* Ab = A  + (size_t)bm * 128 * K;
  const u16* Bb = Bm + (size_t)bn * 128 * K;

  for (int k0 = 0; k0 < K; k0 += 32) {
    __syncthreads();
    for (int j = 0; j < 2; j++) {
      int slot = (wave*2 + j)*64 + lane;
      int r = slot >> 2, c = (slot & 3) * 8;
      async16(&Ab[(size_t)r * K + k0 + c], &As[(wave*2 + j) * 512]);
      async16(&Bb[(size_t)r * K + k0 + c], &Bs[(wave*2 + j) * 512]);
    }
    __syncthreads();
    bf16x8 af[4], bfr[4];
    for (int mi = 0; mi < 4; mi++) af[mi]  = *(const bf16x8*)&As[(wrow + mi*16 + ln)*32 + qd*8];
    for (int ni = 0; ni < 4; ni++) bfr[ni] = *(const bf16x8*)&Bs[(wcol + ni*16 + ln)*32 + qd*8];
    for (int mi = 0; mi < 4; mi++)
      for (int ni = 0; ni < 4; ni++)
        acc[mi][ni] = __builtin_amdgcn_mfma_f32_16x16x32_bf16(af[mi], bfr[ni], acc[mi][ni], 0, 0, 0);
  }

  for (int ni = 0; ni < 4; ni++) {
    int col = bn*128 + wcol + ni*16 + ln;
    float bv = bias[col];
    for (int mi = 0; mi < 4; mi++)
      for (int r = 0; r < 4; r++) {
        int row = bm*128 + wrow + mi*16 + qd*4 + r;
        out[(size_t)row * C_ + col] = acc[mi][ni][r] + bv;
      }
  }
}

extern "C" void kernel_launch(void* const* d_in, const int* in_sizes, int n_in,
                              void* d_out, int out_size, void* d_ws, size_t ws_size,
                              hipStream_t stream) {
  const float* x     = (const float*)d_in[0];
  const float* w_qkv = (const float*)d_in[1];
  const float* b_qkv = (const float*)d_in[2];
  const float* w_out = (const float*)d_in[3];
  const float* b_out = (const float*)d_in[4];
  float* out = (float*)d_out;

  char* ws = (char*)d_ws;
  u16* x_bf    = (u16*)(ws);
  u16* wqkv_bf = (u16*)(ws + (size_t)8*1024*1024);
  u16* wout_bf = (u16*)(ws + (size_t)14*1024*1024);
  u16* q_bf    = (u16*)(ws + (size_t)16*1024*1024);  // [B,H,N,D], pre-scaled
  u16* k_bf    = (u16*)(ws + (size_t)24*1024*1024);  // blocked
  u16* v_bf    = (u16*)(ws + (size_t)32*1024*1024);  // blocked+swizzled
  u16* a_bf    = (u16*)(ws + (size_t)40*1024*1024);  // [M][C]

  k_f32_to_bf16<<<4096, 256, 0, stream>>>(x, x_bf);
  k_f32_to_bf16<<<3072, 256, 0, stream>>>(w_qkv, wqkv_bf);
  k_f32_to_bf16<<<1024, 256, 0, stream>>>(w_out, wout_bf);
  k_gemm_qkv<<<dim3(32, 24), 256, 0, stream>>>(x_bf, wqkv_bf, b_qkv, q_bf, k_bf, v_bf);
  k_attn<<<512, 256, 0, stream>>>(q_bf, k_bf, v_bf, a_bf);
  k_gemm_out<<<dim3(32, 8), 256, 0, stream>>>(a_bf, wout_bf, b_out, out);
}

// Round 5
// 199.152 us; speedup vs baseline: 1.9099x; 1.0010x over previous
//
#include <hip/hip_runtime.h>

#define B_    2
#define N_TOK 2048
#define C_    1024
#define H_    16
#define D_    64
#define M_    (B_*N_TOK)   // 4096
#define N3C   3072

typedef unsigned short u16;
typedef unsigned int   u32;

typedef __attribute__((ext_vector_type(8))) short bf16x8;
typedef __attribute__((ext_vector_type(4))) short bf16x4;
typedef __attribute__((ext_vector_type(4))) float f32x4;

__device__ __forceinline__ u16 f2bf(float f) {       // RNE
  u32 u = __float_as_uint(f);
  return (u16)((u + 0x7FFFu + ((u >> 16) & 1u)) >> 16);
}

// K=16 bf16 MFMA
__device__ __forceinline__ f32x4 mfma16(bf16x4 a, bf16x4 b, f32x4 c) {
#if __has_builtin(__builtin_amdgcn_mfma_f32_16x16x16_bf16)
  return __builtin_amdgcn_mfma_f32_16x16x16_bf16(a, b, c, 0, 0, 0);
#elif __has_builtin(__builtin_amdgcn_mfma_f32_16x16x16bf16_1k)
  return __builtin_amdgcn_mfma_f32_16x16x16bf16_1k(a, b, c, 0, 0, 0);
#else
  asm("v_mfma_f32_16x16x16_bf16 %0, %1, %2, %0" : "+v"(c) : "v"(a), "v"(b));
  return c;
#endif
}

// async global->LDS, 16B/lane; LDS dest = wave-uniform base + lane*16
__device__ __forceinline__ void async16(const u16* g, u16* l) {
  __builtin_amdgcn_global_load_lds(
      (const __attribute__((address_space(1))) u32*)g,
      (__attribute__((address_space(3))) u32*)l, 16, 0, 0);
}

// ---------------- fused fp32 -> bf16 convert (x, w_qkv, w_out in one launch) ----------------
__global__ void k_cvt(const float* __restrict__ x, const float* __restrict__ wq,
                      const float* __restrict__ wo,
                      u16* __restrict__ xb, u16* __restrict__ wqb, u16* __restrict__ wob) {
  size_t i = ((size_t)blockIdx.x * 256 + threadIdx.x) * 4;
  const size_t n0 = (size_t)M_ * C_;          // 4194304
  const size_t n1 = n0 + (size_t)N3C * C_;    // +3145728
  const float* s; u16* d;
  if (i < n0)      { s = x  + i;        d = xb  + i; }
  else if (i < n1) { s = wq + (i - n0); d = wqb + (i - n0); }
  else             { s = wo + (i - n1); d = wob + (i - n1); }
  float4 v = *(const float4*)s;
  *(ushort4*)d = make_ushort4(f2bf(v.x), f2bf(v.y), f2bf(v.z), f2bf(v.w));
}

// ---------------- GEMM1: qkv = x @ w_qkv^T + b ----------------
// Q -> [B,H,N,D] pre-scaled by 0.125*log2(e).
// K -> blocked [bh][kt:32][c:8][row:64][e:8].
// V -> blocked [bh][kt:32][c:8][drow:64][e:8], keys swizzled (see R4).
__global__ __launch_bounds__(256) void k_gemm_qkv(
    const u16* __restrict__ A, const u16* __restrict__ Bm,
    const float* __restrict__ bias,
    u16* __restrict__ qout, u16* __restrict__ kout, u16* __restrict__ vout)
{
  __shared__ u16 As[128*32];
  __shared__ u16 Bs[128*32];
  const int K = C_;
  int bm = blockIdx.x, bn = blockIdx.y;
  int tid = threadIdx.x;
  int lane = tid & 63, wave = tid >> 6;
  int wrow = (wave >> 1) * 64, wcol = (wave & 1) * 64;
  int qd = lane >> 4, ln = lane & 15;

  f32x4 zero = {0.f, 0.f, 0.f, 0.f};
  f32x4 acc[4][4];
  for (int i = 0; i < 4; i++) for (int j = 0; j < 4; j++) acc[i][j] = zero;

  const u16* Ab = A  + (size_t)bm * 128 * K;
  const u16* Bb = Bm + (size_t)bn * 128 * K;

  for (int k0 = 0; k0 < K; k0 += 32) {
    __syncthreads();
    for (int j = 0; j < 2; j++) {
      int slot = (wave*2 + j)*64 + lane;
      int r = slot >> 2, c = (slot & 3) * 8;
      async16(&Ab[(size_t)r * K + k0 + c], &As[(wave*2 + j) * 512]);
      async16(&Bb[(size_t)r * K + k0 + c], &Bs[(wave*2 + j) * 512]);
    }
    __syncthreads();
    bf16x8 af[4], bfr[4];
    for (int mi = 0; mi < 4; mi++) af[mi]  = *(const bf16x8*)&As[(wrow + mi*16 + ln)*32 + qd*8];
    for (int ni = 0; ni < 4; ni++) bfr[ni] = *(const bf16x8*)&Bs[(wcol + ni*16 + ln)*32 + qd*8];
    for (int mi = 0; mi < 4; mi++)
      for (int ni = 0; ni < 4; ni++)
        acc[mi][ni] = __builtin_amdgcn_mfma_f32_16x16x32_bf16(af[mi], bfr[ni], acc[mi][ni], 0, 0, 0);
  }

  for (int ni = 0; ni < 4; ni++) {
    int nbase = bn*128 + wcol + ni*16 + ln;
    int three = nbase >> 10;        // wave-uniform
    int h = (nbase >> 6) & 15;
    int d = nbase & 63;
    float bv = bias[nbase];
    if (three == 2) {
      for (int mi = 0; mi < 4; mi++) {
        int row0 = bm*128 + wrow + mi*16 + qd*4;
        int b = row0 >> 11, t0 = row0 & 2047;
        int kt = t0 >> 6, w64 = t0 & 63;
        int hf = w64 >> 5, w = w64 & 31, par = w >> 4, qdk = (w >> 2) & 3;
        u16 tmp[4];
        for (int r = 0; r < 4; r++) tmp[r] = f2bf(acc[mi][ni][r] + bv);
        size_t off = (((size_t)(b*H_ + h)*32 + kt)*8 + (hf*4 + qdk))*512 + d*8 + par*4;
        *(ushort4*)&vout[off] = *(ushort4*)tmp;
      }
    } else if (three == 1) {
      int c = d >> 3, e = d & 7;
      for (int mi = 0; mi < 4; mi++) {
        for (int r = 0; r < 4; r++) {
          int row = bm*128 + wrow + mi*16 + qd*4 + r;
          int b = row >> 11, t = row & 2047;
          int kt = t >> 6, r64 = t & 63;
          kout[(((size_t)(b*H_ + h)*32 + kt)*8 + c)*512 + r64*8 + e] = f2bf(acc[mi][ni][r] + bv);
        }
      }
    } else {
      float sc = 0.18033688011f;  // 0.125*log2(e) folded into Q
      for (int mi = 0; mi < 4; mi++) {
        for (int r = 0; r < 4; r++) {
          int row = bm*128 + wrow + mi*16 + qd*4 + r;
          int b = row >> 11, t = row & 2047;
          qout[(((size_t)(b*H_ + h))*N_TOK + t)*D_ + d] = f2bf((acc[mi][ni][r] + bv) * sc);
        }
      }
    }
  }
}

// ---------------- flash attention: LDS-staged K/V, register-resident P ----------------
__global__ __launch_bounds__(256, 2) void k_attn(
    const u16* __restrict__ Q, const u16* __restrict__ Kb, const u16* __restrict__ Vb,
    u16* __restrict__ Oa)   // [B*N][C] bf16
{
  __shared__ u16 Ks[4096];
  __shared__ u16 Vs[4096];
  int ord = blockIdx.x;                 // 0..511
  int xcd = ord & 7, kk = ord >> 3;
  int bh = xcd * 4 + (kk & 3);          // 4 heads per XCD
  int qt = kk >> 2;                     // 0..15
  int b = bh >> 4, h = bh & 15;
  int tid = threadIdx.x, lane = tid & 63, wave = tid >> 6;
  int qd = lane >> 4, ln = lane & 15;

  const u16* Qg = Q  + ((size_t)bh * N_TOK + qt*128 + wave*32) * D_;
  const u16* Kg = Kb + (size_t)bh * 32 * 4096;
  const u16* Vg = Vb + (size_t)bh * 32 * 4096;

  bf16x8 qf[2][2];
  for (int mi = 0; mi < 2; mi++)
    for (int ks = 0; ks < 2; ks++)
      qf[mi][ks] = *(const bf16x8*)&Qg[(mi*16 + ln)*D_ + ks*32 + qd*8];

  f32x4 z = {0.f, 0.f, 0.f, 0.f};
  f32x4 oacc[2][4];
  float lsum[2] = {0.f, 0.f};
  for (int mi = 0; mi < 2; mi++) for (int di = 0; di < 4; di++) oacc[mi][di] = z;

  for (int kt = 0; kt < 32; kt++) {
    __syncthreads();
    const u16* Ktile = Kg + (size_t)kt * 4096;
    const u16* Vtile = Vg + (size_t)kt * 4096;
    for (int j = 0; j < 2; j++) {
      int c0 = j*256 + wave*64;
      async16(&Ktile[(c0 + lane)*8], &Ks[c0*8]);
      async16(&Vtile[(c0 + lane)*8], &Vs[c0*8]);
    }
    __syncthreads();

    bf16x8 kf[4][2];
    for (int nt = 0; nt < 4; nt++)
      for (int ks = 0; ks < 2; ks++)
        kf[nt][ks] = *(const bf16x8*)&Ks[((ks*4 + qd)*64 + nt*16 + ln)*8];
    bf16x8 v8[4][2];
    for (int di = 0; di < 4; di++)
      for (int hf = 0; hf < 2; hf++)
        v8[di][hf] = *(const bf16x8*)&Vs[((hf*4 + qd)*64 + di*16 + ln)*8];

    // S^T tiles: A = K-frag, B = Q-frag
    f32x4 sacc[2][4];
    for (int mi = 0; mi < 2; mi++)
      for (int nt = 0; nt < 4; nt++) {
        sacc[mi][nt] = z;
        for (int ks = 0; ks < 2; ks++)
          sacc[mi][nt] = __builtin_amdgcn_mfma_f32_16x16x32_bf16(kf[nt][ks], qf[mi][ks], sacc[mi][nt], 0, 0, 0);
      }

    // P = exp2(S'); truncate-to-bf16 via v_perm, lsum from SAME truncated bits (bias cancels)
    bf16x4 pf[2][4];
    for (int mi = 0; mi < 2; mi++)
      for (int nt = 0; nt < 4; nt++) {
        u32 e0 = __float_as_uint(__builtin_amdgcn_exp2f(sacc[mi][nt][0]));
        u32 e1 = __float_as_uint(__builtin_amdgcn_exp2f(sacc[mi][nt][1]));
        u32 e2 = __float_as_uint(__builtin_amdgcn_exp2f(sacc[mi][nt][2]));
        u32 e3 = __float_as_uint(__builtin_amdgcn_exp2f(sacc[mi][nt][3]));
        lsum[mi] += __uint_as_float(e0 & 0xffff0000u) + __uint_as_float(e1 & 0xffff0000u)
                  + __uint_as_float(e2 & 0xffff0000u) + __uint_as_float(e3 & 0xffff0000u);
        union { u32 u[2]; bf16x4 v; } pk;
        pk.u[0] = __builtin_amdgcn_perm(e1, e0, 0x07060302u);  // [lo16]=trunc(e0),[hi16]=trunc(e1)
        pk.u[1] = __builtin_amdgcn_perm(e3, e2, 0x07060302u);
        pf[mi][nt] = pk.v;
      }

    for (int mi = 0; mi < 2; mi++)
      for (int di = 0; di < 4; di++)
        for (int nt = 0; nt < 4; nt++) {
          int hf = nt >> 1, s = (nt & 1) * 4;
          bf16x4 vv;
          vv[0] = v8[di][hf][s+0]; vv[1] = v8[di][hf][s+1];
          vv[2] = v8[di][hf][s+2]; vv[3] = v8[di][hf][s+3];
          oacc[mi][di] = mfma16(pf[mi][nt], vv, oacc[mi][di]);
        }
  }

  for (int mi = 0; mi < 2; mi++) {
    float ls = lsum[mi];
    ls += __shfl_xor(ls, 16, 64);
    ls += __shfl_xor(ls, 32, 64);
    float rl[4];
    for (int r = 0; r < 4; r++)
      rl[r] = 1.0f / __shfl(ls, qd*4 + r, 64);
    for (int di = 0; di < 4; di++)
      for (int r = 0; r < 4; r++) {
        int t = qt*128 + wave*32 + mi*16 + qd*4 + r;
        Oa[((size_t)b*N_TOK + t)*C_ + h*D_ + di*16 + ln] = f2bf(oacc[mi][di][r] * rl[r]);
      }
  }
}

// ---------------- GEMM2: out = attn @ w_out^T + b_out (fp32 out) ----------------
// 64x128 tile -> grid 512 = 2 blocks/CU (was 256 = 1/CU)
__global__ __launch_bounds__(256, 2) void k_gemm_out(
    const u16* __restrict__ A, const u16* __restrict__ Bm,
    const float* __restrict__ bias, float* __restrict__ out)
{
  __shared__ u16 As[64*32];    // 4KB
  __shared__ u16 Bs[128*32];   // 8KB
  const int K = C_;
  int bm = blockIdx.x, bn = blockIdx.y;
  int tid = threadIdx.x;
  int lane = tid & 63, wave = tid >> 6;
  int wcol = wave * 32;
  int qd = lane >> 4, ln = lane & 15;

  f32x4 zero = {0.f, 0.f, 0.f, 0.f};
  f32x4 acc[4][2];
  for (int i = 0; i < 4; i++) for (int j = 0; j < 2; j++) acc[i][j] = zero;

  const u16* Ab = A  + (size_t)bm * 64 * K;
  const u16* Bb = Bm + (size_t)bn * 128 * K;

  for (int k0 = 0; k0 < K; k0 += 32) {
    __syncthreads();
    {  // A tile 64x32: 1 chunk per lane
      int slot = wave*64 + lane;
      int r = slot >> 2, c = (slot & 3) * 8;
      async16(&Ab[(size_t)r * K + k0 + c], &As[wave * 512]);
    }
    for (int j = 0; j < 2; j++) {  // B tile 128x32: 2 chunks per lane
      int slot = (wave*2 + j)*64 + lane;
      int r = slot >> 2, c = (slot & 3) * 8;
      async16(&Bb[(size_t)r * K + k0 + c], &Bs[(wave*2 + j) * 512]);
    }
    __syncthreads();
    bf16x8 af[4], bfr[2];
    for (int mi = 0; mi < 4; mi++) af[mi]  = *(const bf16x8*)&As[(mi*16 + ln)*32 + qd*8];
    for (int ni = 0; ni < 2; ni++) bfr[ni] = *(const bf16x8*)&Bs[(wcol + ni*16 + ln)*32 + qd*8];
    for (int mi = 0; mi < 4; mi++)
      for (int ni = 0; ni < 2; ni++)
        acc[mi][ni] = __builtin_amdgcn_mfma_f32_16x16x32_bf16(af[mi], bfr[ni], acc[mi][ni], 0, 0, 0);
  }

  for (int ni = 0; ni < 2; ni++) {
    int col = bn*128 + wcol + ni*16 + ln;
    float bv = bias[col];
    for (int mi = 0; mi < 4; mi++)
      for (int r = 0; r < 4; r++) {
        int row = bm*64 + mi*16 + qd*4 + r;
        out[(size_t)row * C_ + col] = acc[mi][ni][r] + bv;
      }
  }
}

extern "C" void kernel_launch(void* const* d_in, const int* in_sizes, int n_in,
                              void* d_out, int out_size, void* d_ws, size_t ws_size,
                              hipStream_t stream) {
  const float* x     = (const float*)d_in[0];
  const float* w_qkv = (const float*)d_in[1];
  const float* b_qkv = (const float*)d_in[2];
  const float* w_out = (const float*)d_in[3];
  const float* b_out = (const float*)d_in[4];
  float* out = (float*)d_out;

  char* ws = (char*)d_ws;
  u16* x_bf    = (u16*)(ws);
  u16* wqkv_bf = (u16*)(ws + (size_t)8*1024*1024);
  u16* wout_bf = (u16*)(ws + (size_t)14*1024*1024);
  u16* q_bf    = (u16*)(ws + (size_t)16*1024*1024);  // [B,H,N,D], pre-scaled
  u16* k_bf    = (u16*)(ws + (size_t)24*1024*1024);  // blocked
  u16* v_bf    = (u16*)(ws + (size_t)32*1024*1024);  // blocked+swizzled
  u16* a_bf    = (u16*)(ws + (size_t)40*1024*1024);  // [M][C]

  k_cvt<<<8192, 256, 0, stream>>>(x, w_qkv, w_out, x_bf, wqkv_bf, wout_bf);
  k_gemm_qkv<<<dim3(32, 24), 256, 0, stream>>>(x_bf, wqkv_bf, b_qkv, q_bf, k_bf, v_bf);
  k_attn<<<512, 256, 0, stream>>>(q_bf, k_bf, v_bf, a_bf);
  k_gemm_out<<<dim3(64, 8), 256, 0, stream>>>(a_bf, wout_bf, b_out, out);
}

// Round 6
// 197.076 us; speedup vs baseline: 1.9300x; 1.0105x over previous
//
#include <hip/hip_runtime.h>

#define B_    2
#define N_TOK 2048
#define C_    1024
#define H_    16
#define D_    64
#define M_    (B_*N_TOK)   // 4096
#define N3C   3072

typedef unsigned short u16;
typedef unsigned int   u32;

typedef __attribute__((ext_vector_type(8))) short bf16x8;
typedef __attribute__((ext_vector_type(4))) short bf16x4;
typedef __attribute__((ext_vector_type(4))) float f32x4;

__device__ __forceinline__ u16 f2bf(float f) {       // RNE
  u32 u = __float_as_uint(f);
  return (u16)((u + 0x7FFFu + ((u >> 16) & 1u)) >> 16);
}
__device__ __forceinline__ u16 f2bf_fast(float f) {  // round-half-up (P only)
  return (u16)((__float_as_uint(f) + 0x8000u) >> 16);
}

// K=16 bf16 MFMA
__device__ __forceinline__ f32x4 mfma16(bf16x4 a, bf16x4 b, f32x4 c) {
#if __has_builtin(__builtin_amdgcn_mfma_f32_16x16x16_bf16)
  return __builtin_amdgcn_mfma_f32_16x16x16_bf16(a, b, c, 0, 0, 0);
#elif __has_builtin(__builtin_amdgcn_mfma_f32_16x16x16bf16_1k)
  return __builtin_amdgcn_mfma_f32_16x16x16bf16_1k(a, b, c, 0, 0, 0);
#else
  asm("v_mfma_f32_16x16x16_bf16 %0, %1, %2, %0" : "+v"(c) : "v"(a), "v"(b));
  return c;
#endif
}

// async global->LDS, 16B/lane; LDS dest = wave-uniform base + lane*16
__device__ __forceinline__ void async16(const u16* g, u16* l) {
  __builtin_amdgcn_global_load_lds(
      (const __attribute__((address_space(1))) u32*)g,
      (__attribute__((address_space(3))) u32*)l, 16, 0, 0);
}

// ---------------- fused fp32 -> bf16 convert ----------------
__global__ void k_cvt(const float* __restrict__ x, const float* __restrict__ wq,
                      const float* __restrict__ wo,
                      u16* __restrict__ xb, u16* __restrict__ wqb, u16* __restrict__ wob) {
  size_t i = ((size_t)blockIdx.x * 256 + threadIdx.x) * 4;
  const size_t n0 = (size_t)M_ * C_;
  const size_t n1 = n0 + (size_t)N3C * C_;
  const float* s; u16* d;
  if (i < n0)      { s = x  + i;        d = xb  + i; }
  else if (i < n1) { s = wq + (i - n0); d = wqb + (i - n0); }
  else             { s = wo + (i - n1); d = wob + (i - n1); }
  float4 v = *(const float4*)s;
  *(ushort4*)d = make_ushort4(f2bf(v.x), f2bf(v.y), f2bf(v.z), f2bf(v.w));
}

// ---------------- GEMM1: qkv = x @ w_qkv^T + b ----------------
// Q -> [B,H,N,D] pre-scaled by 0.125*log2(e).
// K -> blocked [bh][t32:64][c:8][row:32][e:8]: elem (key=t32*32+row, d=c*8+e).
// V -> blocked [bh][t32:64][c:4][drow:64][e:8], keys swizzled within 32-key tile:
//     key w = par*16 + qdk*4 + i  stored at chunk c=qdk, elem e=par*4+i.
__global__ __launch_bounds__(256) void k_gemm_qkv(
    const u16* __restrict__ A, const u16* __restrict__ Bm,
    const float* __restrict__ bias,
    u16* __restrict__ qout, u16* __restrict__ kout, u16* __restrict__ vout)
{
  __shared__ u16 As[128*32];
  __shared__ u16 Bs[128*32];
  const int K = C_;
  int bm = blockIdx.x, bn = blockIdx.y;
  int tid = threadIdx.x;
  int lane = tid & 63, wave = tid >> 6;
  int wrow = (wave >> 1) * 64, wcol = (wave & 1) * 64;
  int qd = lane >> 4, ln = lane & 15;

  f32x4 zero = {0.f, 0.f, 0.f, 0.f};
  f32x4 acc[4][4];
  for (int i = 0; i < 4; i++) for (int j = 0; j < 4; j++) acc[i][j] = zero;

  const u16* Ab = A  + (size_t)bm * 128 * K;
  const u16* Bb = Bm + (size_t)bn * 128 * K;

  for (int k0 = 0; k0 < K; k0 += 32) {
    __syncthreads();
    for (int j = 0; j < 2; j++) {
      int slot = (wave*2 + j)*64 + lane;
      int r = slot >> 2, c = (slot & 3) * 8;
      async16(&Ab[(size_t)r * K + k0 + c], &As[(wave*2 + j) * 512]);
      async16(&Bb[(size_t)r * K + k0 + c], &Bs[(wave*2 + j) * 512]);
    }
    __syncthreads();
    bf16x8 af[4], bfr[4];
    for (int mi = 0; mi < 4; mi++) af[mi]  = *(const bf16x8*)&As[(wrow + mi*16 + ln)*32 + qd*8];
    for (int ni = 0; ni < 4; ni++) bfr[ni] = *(const bf16x8*)&Bs[(wcol + ni*16 + ln)*32 + qd*8];
    for (int mi = 0; mi < 4; mi++)
      for (int ni = 0; ni < 4; ni++)
        acc[mi][ni] = __builtin_amdgcn_mfma_f32_16x16x32_bf16(af[mi], bfr[ni], acc[mi][ni], 0, 0, 0);
  }

  for (int ni = 0; ni < 4; ni++) {
    int nbase = bn*128 + wcol + ni*16 + ln;
    int three = nbase >> 10;        // wave-uniform
    int h = (nbase >> 6) & 15;
    int d = nbase & 63;
    float bv = bias[nbase];
    if (three == 2) {
      // V blocked+swizzled: 4 consecutive keys (r=0..3) -> one 8B store
      for (int mi = 0; mi < 4; mi++) {
        int row0 = bm*128 + wrow + mi*16 + qd*4;
        int b = row0 >> 11, t0 = row0 & 2047;
        int t32 = t0 >> 5, w0 = t0 & 31;
        int par = w0 >> 4;              // qdk == qd here
        u16 tmp[4];
        for (int r = 0; r < 4; r++) tmp[r] = f2bf(acc[mi][ni][r] + bv);
        size_t off = ((size_t)(b*H_ + h)*64 + t32)*2048 + (qd*64 + d)*8 + par*4;
        *(ushort4*)&vout[off] = *(ushort4*)tmp;
      }
    } else if (three == 1) {
      int c = d >> 3, e = d & 7;
      for (int mi = 0; mi < 4; mi++) {
        for (int r = 0; r < 4; r++) {
          int row = bm*128 + wrow + mi*16 + qd*4 + r;
          int b = row >> 11, t = row & 2047;
          int t32 = t >> 5, r32 = t & 31;
          kout[((size_t)(b*H_ + h)*64 + t32)*2048 + (c*32 + r32)*8 + e] = f2bf(acc[mi][ni][r] + bv);
        }
      }
    } else {
      float sc = 0.18033688011f;  // 0.125*log2(e) folded into Q
      for (int mi = 0; mi < 4; mi++) {
        for (int r = 0; r < 4; r++) {
          int row = bm*128 + wrow + mi*16 + qd*4 + r;
          int b = row >> 11, t = row & 2047;
          qout[(((size_t)(b*H_ + h))*N_TOK + t)*D_ + d] = f2bf((acc[mi][ni][r] + bv) * sc);
        }
      }
    }
  }
}

// ---------------- flash attention: key-split waves, barrier-free k-loop ----------------
// block = 64 q-rows; wave w processes 32-key tiles t32 = w, w+4, ... (all 64 rows).
// Private per-wave LDS staging (8 KB) -> no __syncthreads in loop, s_waitcnt only.
// End: parallel O/lsum reduction via LDS (regions reuse dead staging), 2 barriers.
__global__ __launch_bounds__(256, 2) void k_attn(
    const u16* __restrict__ Q, const u16* __restrict__ Kb, const u16* __restrict__ Vb,
    u16* __restrict__ Oa)   // [B*N][C] bf16
{
  __shared__ __align__(16) u16 smem[33280];  // 65 KB: [0,64KB)=staging(32KB)+O-regions, tail=lsum
  int ord = blockIdx.x;                 // 0..1023
  int xcd = ord & 7, kk = ord >> 3;     // kk 0..127
  int bh = xcd * 4 + (kk & 3);          // 4 heads per XCD -> K/V L2-resident
  int qt = kk >> 2;                     // 0..31
  int b = bh >> 4, h = bh & 15;
  int tid = threadIdx.x, lane = tid & 63, wave = tid >> 6;
  int qd = lane >> 4, ln = lane & 15;

  u16* KsW = smem + wave * 4096;        // private 4KB K tile
  u16* VsW = KsW + 2048;                // private 4KB V tile
  float* lsumF = (float*)&smem[32768];  // [src:4][mi:4][ln:16] floats

  const u16* Qg  = Q  + ((size_t)bh * N_TOK + qt*64) * D_;
  const u16* KgB = Kb + (size_t)bh * 64 * 2048;
  const u16* VgB = Vb + (size_t)bh * 64 * 2048;

  // loop-invariant Q B-fragments (pre-scaled by 0.125*log2e), 4 strips of 16 rows
  bf16x8 qf[4][2];
  for (int mi = 0; mi < 4; mi++)
    for (int ks = 0; ks < 2; ks++)
      qf[mi][ks] = *(const bf16x8*)&Qg[(mi*16 + ln)*D_ + ks*32 + qd*8];

  f32x4 z = {0.f, 0.f, 0.f, 0.f};
  f32x4 oacc[4][4];
  float lsum[4] = {0.f, 0.f, 0.f, 0.f};
  for (int mi = 0; mi < 4; mi++) for (int di = 0; di < 4; di++) oacc[mi][di] = z;

  for (int t32 = wave; t32 < 64; t32 += 4) {
    const u16* Kt = KgB + (size_t)t32 * 2048;
    const u16* Vt = VgB + (size_t)t32 * 2048;
    for (int j = 0; j < 4; j++) async16(&Kt[j*512 + lane*8], &KsW[j*512]);
    for (int j = 0; j < 4; j++) async16(&Vt[j*512 + lane*8], &VsW[j*512]);
    __builtin_amdgcn_s_waitcnt(0);   // wave-private drain (no barrier needed)

    bf16x8 kf[2][2];
    for (int nt = 0; nt < 2; nt++)
      for (int ks = 0; ks < 2; ks++)
        kf[nt][ks] = *(const bf16x8*)&KsW[((ks*4 + qd)*32 + nt*16 + ln)*8];
    bf16x8 v8[4];
    for (int di = 0; di < 4; di++)
      v8[di] = *(const bf16x8*)&VsW[(qd*64 + di*16 + ln)*8];

    // S^T tiles: A = K-frag, B = Q-frag -> sacc[mi][nt][r] = S[q=mi*16+ln][key=nt*16+qd*4+r]
    f32x4 sacc[4][2];
    for (int mi = 0; mi < 4; mi++)
      for (int nt = 0; nt < 2; nt++) {
        sacc[mi][nt] = z;
        for (int ks = 0; ks < 2; ks++)
          sacc[mi][nt] = __builtin_amdgcn_mfma_f32_16x16x32_bf16(kf[nt][ks], qf[mi][ks], sacc[mi][nt], 0, 0, 0);
      }

    // P = exp2(S'), pack to K=16 A-frag, PV immediately (register-resident P)
    for (int mi = 0; mi < 4; mi++)
      for (int nt = 0; nt < 2; nt++) {
        bf16x4 pf;
        for (int i = 0; i < 4; i++) {
          float e = __builtin_amdgcn_exp2f(sacc[mi][nt][i]);
          lsum[mi] += e;
          pf[i] = (short)f2bf_fast(e);
        }
        for (int di = 0; di < 4; di++) {
          bf16x4 vv;
          vv[0] = v8[di][nt*4+0]; vv[1] = v8[di][nt*4+1];
          vv[2] = v8[di][nt*4+2]; vv[3] = v8[di][nt*4+3];
          oacc[mi][di] = mfma16(pf, vv, oacc[mi][di]);
        }
      }
  }

  // lsum wave-partials: reduce over qd, store [wave][mi][ln]
  for (int mi = 0; mi < 4; mi++) {
    float ls = lsum[mi];
    ls += __shfl_xor(ls, 16, 64);
    ls += __shfl_xor(ls, 32, 64);
    if (qd == 0) lsumF[wave*64 + mi*16 + ln] = ls;
  }
  __syncthreads();   // #1: all staging reads + lsum writes done

  // O partials -> region[wave] (reuses staging LDS), slot ((mi*4+di)*4+qd)*16+ln
  float* Rw = (float*)smem + wave * 4096;
  for (int mi = 0; mi < 4; mi++)
    for (int di = 0; di < 4; di++)
      *(f32x4*)&Rw[(((mi*4 + di)*4 + qd)*16 + ln)*4] = oacc[mi][di];
  __syncthreads();   // #2

  // each wave reduces strip mi=wave across the 4 regions, normalizes, writes out
  {
    int mi = wave;
    float rs[4];
    for (int r = 0; r < 4; r++) {
      int q = mi*16 + qd*4 + r;   // lsumF index uses within-strip row = qd*4+r
      rs[r] = 1.0f / (lsumF[0*64 + mi*16 + qd*4 + r] + lsumF[1*64 + mi*16 + qd*4 + r]
                    + lsumF[2*64 + mi*16 + qd*4 + r] + lsumF[3*64 + mi*16 + qd*4 + r]);
      (void)q;
    }
    for (int di = 0; di < 4; di++) {
      f32x4 osum = z;
      for (int src = 0; src < 4; src++)
        osum += *(const f32x4*)&((float*)smem)[src*4096*1 + ((((mi*4 + di)*4 + qd)*16 + ln)*4)];
      for (int r = 0; r < 4; r++) {
        int t = qt*64 + mi*16 + qd*4 + r;
        Oa[((size_t)b*N_TOK + t)*C_ + h*D_ + di*16 + ln] = f2bf(osum[r] * rs[r]);
      }
    }
  }
}

// ---------------- GEMM2: out = attn @ w_out^T + b_out (fp32 out), 64x128 tile ----------------
__global__ __launch_bounds__(256, 2) void k_gemm_out(
    const u16* __restrict__ A, const u16* __restrict__ Bm,
    const float* __restrict__ bias, float* __restrict__ out)
{
  __shared__ u16 As[64*32];
  __shared__ u16 Bs[128*32];
  const int K = C_;
  int bm = blockIdx.x, bn = blockIdx.y;
  int tid = threadIdx.x;
  int lane = tid & 63, wave = tid >> 6;
  int wcol = wave * 32;
  int qd = lane >> 4, ln = lane & 15;

  f32x4 zero = {0.f, 0.f, 0.f, 0.f};
  f32x4 acc[4][2];
  for (int i = 0; i < 4; i++) for (int j = 0; j < 2; j++) acc[i][j] = zero;

  const u16* Ab = A  + (size_t)bm * 64 * K;
  const u16* Bb = Bm + (size_t)bn * 128 * K;

  for (int k0 = 0; k0 < K; k0 += 32) {
    __syncthreads();
    {
      int slot = wave*64 + lane;
      int r = slot >> 2, c = (slot & 3) * 8;
      async16(&Ab[(size_t)r * K + k0 + c], &As[wave * 512]);
    }
    for (int j = 0; j < 2; j++) {
      int slot = (wave*2 + j)*64 + lane;
      int r = slot >> 2, c = (slot & 3) * 8;
      async16(&Bb[(size_t)r * K + k0 + c], &Bs[(wave*2 + j) * 512]);
    }
    __syncthreads();
    bf16x8 af[4], bfr[2];
    for (int mi = 0; mi < 4; mi++) af[mi]  = *(const bf16x8*)&As[(mi*16 + ln)*32 + qd*8];
    for (int ni = 0; ni < 2; ni++) bfr[ni] = *(const bf16x8*)&Bs[(wcol + ni*16 + ln)*32 + qd*8];
    for (int mi = 0; mi < 4; mi++)
      for (int ni = 0; ni < 2; ni++)
        acc[mi][ni] = __builtin_amdgcn_mfma_f32_16x16x32_bf16(af[mi], bfr[ni], acc[mi][ni], 0, 0, 0);
  }

  for (int ni = 0; ni < 2; ni++) {
    int col = bn*128 + wcol + ni*16 + ln;
    float bv = bias[col];
    for (int mi = 0; mi < 4; mi++)
      for (int r = 0; r < 4; r++) {
        int row = bm*64 + mi*16 + qd*4 + r;
        out[(size_t)row * C_ + col] = acc[mi][ni][r] + bv;
      }
  }
}

extern "C" void kernel_launch(void* const* d_in, const int* in_sizes, int n_in,
                              void* d_out, int out_size, void* d_ws, size_t ws_size,
                              hipStream_t stream) {
  const float* x     = (const float*)d_in[0];
  const float* w_qkv = (const float*)d_in[1];
  const float* b_qkv = (const float*)d_in[2];
  const float* w_out = (const float*)d_in[3];
  const float* b_out = (const float*)d_in[4];
  float* out = (float*)d_out;

  char* ws = (char*)d_ws;
  u16* x_bf    = (u16*)(ws);
  u16* wqkv_bf = (u16*)(ws + (size_t)8*1024*1024);
  u16* wout_bf = (u16*)(ws + (size_t)14*1024*1024);
  u16* q_bf    = (u16*)(ws + (size_t)16*1024*1024);  // [B,H,N,D], pre-scaled
  u16* k_bf    = (u16*)(ws + (size_t)24*1024*1024);  // blocked [bh][t32][c8][row32][e8]
  u16* v_bf    = (u16*)(ws + (size_t)32*1024*1024);  // blocked [bh][t32][c4][drow64][e8]
  u16* a_bf    = (u16*)(ws + (size_t)40*1024*1024);  // [M][C]

  k_cvt<<<8192, 256, 0, stream>>>(x, w_qkv, w_out, x_bf, wqkv_bf, wout_bf);
  k_gemm_qkv<<<dim3(32, 24), 256, 0, stream>>>(x_bf, wqkv_bf, b_qkv, q_bf, k_bf, v_bf);
  k_attn<<<1024, 256, 0, stream>>>(q_bf, k_bf, v_bf, a_bf);
  k_gemm_out<<<dim3(64, 8), 256, 0, stream>>>(a_bf, wout_bf, b_out, out);
}

// Round 7
// 170.879 us; speedup vs baseline: 2.2259x; 1.1533x over previous
//
#include <hip/hip_runtime.h>

#define B_    2
#define N_TOK 2048
#define C_    1024
#define H_    16
#define D_    64
#define M_    (B_*N_TOK)   // 4096
#define N3C   3072

typedef unsigned short u16;
typedef unsigned int   u32;

typedef __attribute__((ext_vector_type(8))) short bf16x8;
typedef __attribute__((ext_vector_type(4))) float f32x4;

__device__ __forceinline__ u16 f2bf(float f) {       // RNE
  u32 u = __float_as_uint(f);
  return (u16)((u + 0x7FFFu + ((u >> 16) & 1u)) >> 16);
}
__device__ __forceinline__ u16 f2bf_fast(float f) {  // round-half-up (P only)
  return (u16)((__float_as_uint(f) + 0x8000u) >> 16);
}

// async global->LDS, 16B/lane; LDS dest = wave-uniform base + lane*16
__device__ __forceinline__ void async16(const u16* g, u16* l) {
  __builtin_amdgcn_global_load_lds(
      (const __attribute__((address_space(1))) u32*)g,
      (__attribute__((address_space(3))) u32*)l, 16, 0, 0);
}

// ---------------- fused fp32 -> bf16 convert ----------------
__global__ void k_cvt(const float* __restrict__ x, const float* __restrict__ wq,
                      const float* __restrict__ wo,
                      u16* __restrict__ xb, u16* __restrict__ wqb, u16* __restrict__ wob) {
  size_t i = ((size_t)blockIdx.x * 256 + threadIdx.x) * 4;
  const size_t n0 = (size_t)M_ * C_;
  const size_t n1 = n0 + (size_t)N3C * C_;
  const float* s; u16* d;
  if (i < n0)      { s = x  + i;        d = xb  + i; }
  else if (i < n1) { s = wq + (i - n0); d = wqb + (i - n0); }
  else             { s = wo + (i - n1); d = wob + (i - n1); }
  float4 v = *(const float4*)s;
  *(ushort4*)d = make_ushort4(f2bf(v.x), f2bf(v.y), f2bf(v.z), f2bf(v.w));
}

// ---------------- GEMM1: qkv = x @ w_qkv^T + b   (BK=64, swizzled staging) ----------------
// Q -> [B,H,N,D] pre-scaled by 0.125*log2(e).
// K -> blocked [bh][t32:64][c:8][row:32][e:8], rows PERMUTED: key w at row
//      p(w) = ((w>>2)&1)*16 + ((w>>3)&3)*4 + (w&3)  (makes S^T C-layout == K=32 A-frag).
// V -> [b,h,d,N], key-chunks XOR-swizzled: chunk' = ((t>>3)&7) ^ (d&7).
__global__ __launch_bounds__(256, 3) void k_gemm_qkv(
    const u16* __restrict__ A, const u16* __restrict__ Bm,
    const float* __restrict__ bias,
    u16* __restrict__ qout, u16* __restrict__ kout, u16* __restrict__ vout)
{
  __shared__ u16 As[128*64];   // 16 KB
  __shared__ u16 Bs[128*64];   // 16 KB
  const int K = C_;
  int bm = blockIdx.x, bn = blockIdx.y;
  int tid = threadIdx.x;
  int lane = tid & 63, wave = tid >> 6;
  int wrow = (wave >> 1) * 64, wcol = (wave & 1) * 64;
  int qd = lane >> 4, ln = lane & 15;

  f32x4 zero = {0.f, 0.f, 0.f, 0.f};
  f32x4 acc[4][4];
  for (int i = 0; i < 4; i++) for (int j = 0; j < 4; j++) acc[i][j] = zero;

  const u16* Ab = A  + (size_t)bm * 128 * K;
  const u16* Bb = Bm + (size_t)bn * 128 * K;

  for (int k0 = 0; k0 < K; k0 += 64) {
    __syncthreads();
    for (int j = 0; j < 4; j++) {
      int slot = (wave*4 + j)*64 + lane;
      int r = slot >> 3, kc = slot & 7;
      int c = (kc ^ (r & 7)) * 8;          // XOR swizzle (LDS dest is forced contiguous)
      async16(&Ab[(size_t)r * K + k0 + c], &As[(wave*4 + j) * 512]);
      async16(&Bb[(size_t)r * K + k0 + c], &Bs[(wave*4 + j) * 512]);
    }
    __syncthreads();
    for (int kk2 = 0; kk2 < 2; kk2++) {
      bf16x8 af[4], bfr[4];
      for (int mi = 0; mi < 4; mi++) {
        int row = wrow + mi*16 + ln;
        af[mi] = *(const bf16x8*)&As[(row*8 + ((kk2*4 + qd) ^ (ln & 7)))*8];
      }
      for (int ni = 0; ni < 4; ni++) {
        int row = wcol + ni*16 + ln;
        bfr[ni] = *(const bf16x8*)&Bs[(row*8 + ((kk2*4 + qd) ^ (ln & 7)))*8];
      }
      for (int mi = 0; mi < 4; mi++)
        for (int ni = 0; ni < 4; ni++)
          acc[mi][ni] = __builtin_amdgcn_mfma_f32_16x16x32_bf16(af[mi], bfr[ni], acc[mi][ni], 0, 0, 0);
    }
  }

  for (int ni = 0; ni < 4; ni++) {
    int nbase = bn*128 + wcol + ni*16 + ln;
    int three = nbase >> 10;        // wave-uniform
    int h = (nbase >> 6) & 15;
    int d = nbase & 63;
    float bv = bias[nbase];
    if (three == 2) {
      // V: [b,h,d,N] with XOR'd key chunks; 4 consecutive keys -> one 8B store
      for (int mi = 0; mi < 4; mi++) {
        int row0 = bm*128 + wrow + mi*16 + qd*4;
        int b = row0 >> 11, t0 = row0 & 2047;
        int chunkp = ((t0 >> 3) & 7) ^ (d & 7);
        u16 tmp[4];
        for (int r = 0; r < 4; r++) tmp[r] = f2bf(acc[mi][ni][r] + bv);
        size_t off = ((size_t)(b*H_ + h)*D_ + d)*N_TOK + (t0 >> 6)*64 + chunkp*8 + (t0 & 7);
        *(ushort4*)&vout[off] = *(ushort4*)tmp;
      }
    } else if (three == 1) {
      // K blocked, rows permuted by p(w)
      int c = d >> 3, e = d & 7;
      for (int mi = 0; mi < 4; mi++) {
        for (int r = 0; r < 4; r++) {
          int row = bm*128 + wrow + mi*16 + qd*4 + r;
          int b = row >> 11, t = row & 2047;
          int t32 = t >> 5, w = t & 31;
          int p = ((w >> 2) & 1)*16 + ((w >> 3) & 3)*4 + (w & 3);
          kout[((size_t)(b*H_ + h)*64 + t32)*2048 + (c*32 + p)*8 + e] = f2bf(acc[mi][ni][r] + bv);
        }
      }
    } else {
      float sc = 0.18033688011f;  // 0.125*log2(e) folded into Q
      for (int mi = 0; mi < 4; mi++) {
        for (int r = 0; r < 4; r++) {
          int row = bm*128 + wrow + mi*16 + qd*4 + r;
          int b = row >> 11, t = row & 2047;
          qout[(((size_t)(b*H_ + h))*N_TOK + t)*D_ + d] = f2bf((acc[mi][ni][r] + bv) * sc);
        }
      }
    }
  }
}

// ---------------- flash attention: shared K/V tiles, K=32 PV via key permutation ----------------
// block = 4 waves x 32 q-rows = 128 rows; grid 512 (XCD-swizzled) -> 2 blocks/CU.
// S^T (A=K permuted-rows, B=Q) exits with lane qd holding keys qd*8+{nt_h*4+r} ==
// exactly the 16x16x32 A-fragment -> PV in K=32 MFMAs straight from registers.
__global__ __launch_bounds__(256, 2) void k_attn(
    const u16* __restrict__ Q, const u16* __restrict__ Kb, const u16* __restrict__ Vb,
    u16* __restrict__ Oa)   // [B*N][C] bf16
{
  __shared__ u16 Ks[4096];   // two 32-key tiles: [pair:2][c:8][row:32][e:8]
  __shared__ u16 Vs[4096];   // [d:64][chunk':8][e:8], chunk' = kc ^ (d&7)
  int ord = blockIdx.x;                 // 0..511
  int xcd = ord & 7, kk = ord >> 3;
  int bh = xcd * 4 + (kk & 3);          // 4 heads per XCD -> K/V L2-resident
  int qt = kk >> 2;                     // 0..15
  int b = bh >> 4, h = bh & 15;
  int tid = threadIdx.x, lane = tid & 63, wave = tid >> 6;
  int qd = lane >> 4, ln = lane & 15;

  const u16* Qg = Q  + ((size_t)bh * N_TOK + qt*128 + wave*32) * D_;
  const u16* Kg = Kb + (size_t)bh * 64 * 2048;
  const u16* Vg = Vb + (size_t)bh * (size_t)D_ * N_TOK;

  bf16x8 qf[2][2];
  for (int mi = 0; mi < 2; mi++)
    for (int ks = 0; ks < 2; ks++)
      qf[mi][ks] = *(const bf16x8*)&Qg[(mi*16 + ln)*D_ + ks*32 + qd*8];

  f32x4 z = {0.f, 0.f, 0.f, 0.f};
  f32x4 oacc[2][4];
  float lsum[2] = {0.f, 0.f};
  for (int mi = 0; mi < 2; mi++) for (int di = 0; di < 4; di++) oacc[mi][di] = z;

  for (int kt = 0; kt < 32; kt++) {     // 64 keys per iteration
    __syncthreads();
    const u16* Kt = Kg + (size_t)kt * 4096;   // two consecutive 32-key blocked tiles
    for (int j = 0; j < 2; j++) {
      int c0 = j*256 + wave*64;
      async16(&Kt[(c0 + lane)*8], &Ks[c0*8]);
      int cc = c0 + lane;
      int d = cc >> 3, kcp = cc & 7;          // LDS holds swizzled chunks as-is
      async16(&Vg[(size_t)d*N_TOK + kt*64 + kcp*8], &Vs[c0*8]);
    }
    __syncthreads();

    bf16x8 kf[4][2];
    for (int nt = 0; nt < 4; nt++)
      for (int ksd = 0; ksd < 2; ksd++)
        kf[nt][ksd] = *(const bf16x8*)&Ks[(nt>>1)*2048 + ((ksd*4 + qd)*32 + (nt&1)*16 + ln)*8];
    bf16x8 vf[4][2];
    for (int di = 0; di < 4; di++)
      for (int hf = 0; hf < 2; hf++) {
        int d = di*16 + ln;
        vf[di][hf] = *(const bf16x8*)&Vs[(d*8 + ((hf*4 + qd) ^ (ln & 7)))*8];
      }

    // S^T: rows = permuted key positions; sacc[mi][nt][r] at lane qd = key qd*8+(nt&1)*4+r of half nt>>1
    f32x4 sacc[2][4];
    for (int mi = 0; mi < 2; mi++)
      for (int nt = 0; nt < 4; nt++) {
        sacc[mi][nt] = z;
        for (int ksd = 0; ksd < 2; ksd++)
          sacc[mi][nt] = __builtin_amdgcn_mfma_f32_16x16x32_bf16(kf[nt][ksd], qf[mi][ksd], sacc[mi][nt], 0, 0, 0);
      }

    // P = exp2(S'); two f32x4 -> one K=32 A-frag; PV with half the MFMA count
    for (int mi = 0; mi < 2; mi++)
      for (int hf = 0; hf < 2; hf++) {
        union { u16 s[8]; bf16x8 v; } pk;
        for (int nth = 0; nth < 2; nth++)
          for (int i = 0; i < 4; i++) {
            float e = __builtin_amdgcn_exp2f(sacc[mi][hf*2 + nth][i]);
            lsum[mi] += e;
            pk.s[nth*4 + i] = f2bf_fast(e);
          }
        for (int di = 0; di < 4; di++)
          oacc[mi][di] = __builtin_amdgcn_mfma_f32_16x16x32_bf16(pk.v, vf[di][hf], oacc[mi][di], 0, 0, 0);
      }
  }

  for (int mi = 0; mi < 2; mi++) {
    float ls = lsum[mi];
    ls += __shfl_xor(ls, 16, 64);
    ls += __shfl_xor(ls, 32, 64);
    float rl[4];
    for (int r = 0; r < 4; r++)
      rl[r] = 1.0f / __shfl(ls, qd*4 + r, 64);
    for (int di = 0; di < 4; di++)
      for (int r = 0; r < 4; r++) {
        int t = qt*128 + wave*32 + mi*16 + qd*4 + r;
        Oa[((size_t)b*N_TOK + t)*C_ + h*D_ + di*16 + ln] = f2bf(oacc[mi][di][r] * rl[r]);
      }
  }
}

// ---------------- GEMM2: out = attn @ w_out^T + b_out (fp32 out), 64x128 tile ----------------
__global__ __launch_bounds__(256, 2) void k_gemm_out(
    const u16* __restrict__ A, const u16* __restrict__ Bm,
    const float* __restrict__ bias, float* __restrict__ out)
{
  __shared__ u16 As[64*32];
  __shared__ u16 Bs[128*32];
  const int K = C_;
  int bm = blockIdx.x, bn = blockIdx.y;
  int tid = threadIdx.x;
  int lane = tid & 63, wave = tid >> 6;
  int wcol = wave * 32;
  int qd = lane >> 4, ln = lane & 15;

  f32x4 zero = {0.f, 0.f, 0.f, 0.f};
  f32x4 acc[4][2];
  for (int i = 0; i < 4; i++) for (int j = 0; j < 2; j++) acc[i][j] = zero;

  const u16* Ab = A  + (size_t)bm * 64 * K;
  const u16* Bb = Bm + (size_t)bn * 128 * K;

  for (int k0 = 0; k0 < K; k0 += 32) {
    __syncthreads();
    {
      int slot = wave*64 + lane;
      int r = slot >> 2, c = (slot & 3) * 8;
      async16(&Ab[(size_t)r * K + k0 + c], &As[wave * 512]);
    }
    for (int j = 0; j < 2; j++) {
      int slot = (wave*2 + j)*64 + lane;
      int r = slot >> 2, c = (slot & 3) * 8;
      async16(&Bb[(size_t)r * K + k0 + c], &Bs[(wave*2 + j) * 512]);
    }
    __syncthreads();
    bf16x8 af[4], bfr[2];
    for (int mi = 0; mi < 4; mi++) af[mi]  = *(const bf16x8*)&As[(mi*16 + ln)*32 + qd*8];
    for (int ni = 0; ni < 2; ni++) bfr[ni] = *(const bf16x8*)&Bs[(wcol + ni*16 + ln)*32 + qd*8];
    for (int mi = 0; mi < 4; mi++)
      for (int ni = 0; ni < 2; ni++)
        acc[mi][ni] = __builtin_amdgcn_mfma_f32_16x16x32_bf16(af[mi], bfr[ni], acc[mi][ni], 0, 0, 0);
  }

  for (int ni = 0; ni < 2; ni++) {
    int col = bn*128 + wcol + ni*16 + ln;
    float bv = bias[col];
    for (int mi = 0; mi < 4; mi++)
      for (int r = 0; r < 4; r++) {
        int row = bm*64 + mi*16 + qd*4 + r;
        out[(size_t)row * C_ + col] = acc[mi][ni][r] + bv;
      }
  }
}

extern "C" void kernel_launch(void* const* d_in, const int* in_sizes, int n_in,
                              void* d_out, int out_size, void* d_ws, size_t ws_size,
                              hipStream_t stream) {
  const float* x     = (const float*)d_in[0];
  const float* w_qkv = (const float*)d_in[1];
  const float* b_qkv = (const float*)d_in[2];
  const float* w_out = (const float*)d_in[3];
  const float* b_out = (const float*)d_in[4];
  float* out = (float*)d_out;

  char* ws = (char*)d_ws;
  u16* x_bf    = (u16*)(ws);
  u16* wqkv_bf = (u16*)(ws + (size_t)8*1024*1024);
  u16* wout_bf = (u16*)(ws + (size_t)14*1024*1024);
  u16* q_bf    = (u16*)(ws + (size_t)16*1024*1024);  // [B,H,N,D], pre-scaled
  u16* k_bf    = (u16*)(ws + (size_t)24*1024*1024);  // blocked, rows permuted
  u16* v_bf    = (u16*)(ws + (size_t)32*1024*1024);  // [b,h,d,N], chunks XOR-swizzled
  u16* a_bf    = (u16*)(ws + (size_t)40*1024*1024);  // [M][C]

  k_cvt<<<8192, 256, 0, stream>>>(x, w_qkv, w_out, x_bf, wqkv_bf, wout_bf);
  k_gemm_qkv<<<dim3(32, 24), 256, 0, stream>>>(x_bf, wqkv_bf, b_qkv, q_bf, k_bf, v_bf);
  k_attn<<<512, 256, 0, stream>>>(q_bf, k_bf, v_bf, a_bf);
  k_gemm_out<<<dim3(64, 8), 256, 0, stream>>>(a_bf, wout_bf, b_out, out);
}